// Round 1
// baseline (28.350 us; speedup 1.0000x reference)
//
#include <hip/hip_runtime.h>

#define CLS 512
#define NROWS 32768
#define WPB 4              // waves per block
#define NBLOCKS 2048
#define TOTAL_WAVES (NBLOCKS * WPB)   // 8192 -> 4 rows per wave

__global__ __launch_bounds__(256) void lr_partial_kernel(
    const float* __restrict__ out, const int* __restrict__ tgt,
    float* __restrict__ partial) {
  const int lane = threadIdx.x & 63;
  const int wid  = threadIdx.x >> 6;
  const int gw   = blockIdx.x * WPB + wid;

  float acc = 0.0f;

  for (int row = gw; row < NROWS; row += TOTAL_WAVES) {
    const float4* po = reinterpret_cast<const float4*>(out + (size_t)row * CLS) + lane * 2;
    const int4*   pt = reinterpret_cast<const int4*>(tgt + (size_t)row * CLS) + lane * 2;
    float4 o0 = po[0];
    float4 o1 = po[1];
    int4   t0 = pt[0];
    int4   t1 = pt[1];

    float ov[8] = {o0.x, o0.y, o0.z, o0.w, o1.x, o1.y, o1.z, o1.w};
    int   tv[8] = {t0.x, t0.y, t0.z, t0.w, t1.x, t1.y, t1.z, t1.w};

    float s_neg = 0.0f, s_pos = 0.0f;
    int npos = 0;
#pragma unroll
    for (int j = 0; j < 8; ++j) {
      // target is guaranteed 0/1; exp(x) if t==0 else exp(-x)
      float x = tv[j] ? -ov[j] : ov[j];
      float e = __expf(x);
      if (tv[j]) { s_pos += e; npos += 1; }
      else       { s_neg += e; }
    }

    // 64-lane butterfly reduce (all lanes end with the full-row sums)
#pragma unroll
    for (int m = 1; m < 64; m <<= 1) {
      s_neg += __shfl_xor(s_neg, m);
      s_pos += __shfl_xor(s_pos, m);
      npos  += __shfl_xor(npos, m);
    }

    float fpos = (float)npos;
    float fneg = (float)(CLS - npos);
    float num  = fpos * fneg;
    if (num == 0.0f) num = (float)CLS;
    acc += s_neg * s_pos / num;   // same value in every lane
  }

  __shared__ float sacc[WPB];
  if (lane == 0) sacc[wid] = acc;
  __syncthreads();
  if (threadIdx.x == 0) {
    float s = 0.0f;
#pragma unroll
    for (int i = 0; i < WPB; ++i) s += sacc[i];
    partial[blockIdx.x] = s;
  }
}

__global__ __launch_bounds__(256) void lr_final_kernel(
    const float* __restrict__ partial, float* __restrict__ out) {
  const int lane = threadIdx.x & 63;
  const int wid  = threadIdx.x >> 6;

  float s = 0.0f;
  for (int i = threadIdx.x; i < NBLOCKS; i += 256) s += partial[i];

#pragma unroll
  for (int m = 1; m < 64; m <<= 1) s += __shfl_xor(s, m);

  __shared__ float w[4];
  if (lane == 0) w[wid] = s;
  __syncthreads();
  if (threadIdx.x == 0) out[0] = w[0] + w[1] + w[2] + w[3];
}

extern "C" void kernel_launch(void* const* d_in, const int* in_sizes, int n_in,
                              void* d_out, int out_size, void* d_ws, size_t ws_size,
                              hipStream_t stream) {
  const float* output = (const float*)d_in[0];
  const int*   target = (const int*)d_in[1];
  float* partial = (float*)d_ws;          // NBLOCKS floats = 8 KiB
  float* loss    = (float*)d_out;

  lr_partial_kernel<<<NBLOCKS, 256, 0, stream>>>(output, target, partial);
  lr_final_kernel<<<1, 256, 0, stream>>>(partial, loss);
}